// Round 10
// baseline (261.224 us; speedup 1.0000x reference)
//
#include <hip/hip_runtime.h>

#define M_NODES 20000
#define N_EDGES_C 320000
#define DIM 512

// ============ MEASUREMENT ROUND: pre_k(convert), aggregate_k, gemm_k run
// their idempotent bodies x3 so (a) total delta = 2x(conv+agg+gemm) and
// (b) each dispatch exceeds the ~42us poison-fill cutoff -> visible in top-5
// with its own counters. Revert REPS to 1 next round. ============
#define REPS 3

typedef __attribute__((ext_vector_type(4))) float f32x4;
typedef __attribute__((ext_vector_type(4))) __bf16 bf16x4;
typedef __attribute__((ext_vector_type(8))) __bf16 bf16x8;

// ---------------- async global->LDS (16B per lane) ----------------
__device__ __forceinline__ void async16(__bf16* lds, const __bf16* g) {
  __builtin_amdgcn_global_load_lds(
      (const __attribute__((address_space(1))) void*)g,
      (__attribute__((address_space(3))) void*)lds, 16, 0, 0);
}

// ---------------- 0. zero counts ----------------
__global__ __launch_bounds__(256) void zero_k(int4* __restrict__ counts4) {
  const int i = blockIdx.x * 256 + threadIdx.x;
  if (i < M_NODES / 4) counts4[i] = int4{0, 0, 0, 0};
}

// ---------------- 1. fused pre-pass: convert(x3) + W-transpose + count ------
__global__ __launch_bounds__(256) void pre_k(const float* __restrict__ h,
                                             const float* __restrict__ w,
                                             const float* __restrict__ norm,
                                             const int* __restrict__ dst,
                                             __bf16* __restrict__ hb,
                                             __bf16* __restrict__ wT,
                                             int* __restrict__ counts) {
  const int bid = blockIdx.x;
  const int tid = threadIdx.x;
  const int gtid = bid * 256 + tid;
  const int gsz = gridDim.x * 256;

  // convert: hb = bf16(norm[row] * h)  [x REPS, idempotent]
  for (int rep = 0; rep < REPS; ++rep) {
    for (int i = gtid; i < M_NODES * DIM / 4; i += gsz) {
      const int elem = i * 4;
      const float s = norm[elem >> 9];
      f32x4 v = *(const f32x4*)&h[elem];
      bf16x4 o;
      o.x = (__bf16)(v.x * s);
      o.y = (__bf16)(v.y * s);
      o.z = (__bf16)(v.z * s);
      o.w = (__bf16)(v.w * s);
      *(bf16x4*)&hb[elem] = o;
    }
  }

  // weight transpose: blocks 0..255 handle one 32x32 tile each  [x1]
  if (bid < 256) {
    __shared__ float tile[32][33];
    const int bx = (bid & 15) * 32, by = (bid >> 4) * 32;
    const int tx = tid & 31, ty8 = tid >> 5;
#pragma unroll
    for (int st = 0; st < 4; ++st) {
      const int r = ty8 + st * 8;
      tile[r][tx] = w[(by + r) * DIM + bx + tx];
    }
    __syncthreads();
#pragma unroll
    for (int st = 0; st < 4; ++st) {
      const int r = ty8 + st * 8;
      wT[(bx + r) * DIM + by + tx] = (__bf16)tile[tx][r];
    }
  }

  // degree count  [x1 — atomics, not repeatable]
  for (int e = gtid; e < N_EDGES_C; e += gsz) atomicAdd(&counts[dst[e]], 1);
}

// ---------------- 2. scan: 1 block, 250 threads x 80 elements ----------------
__global__ __launch_bounds__(256) void scan_k(int* __restrict__ counts,
                                              int* __restrict__ offsets) {
  __shared__ int wsum2[4];
  const int tid = threadIdx.x;
  const int lane = tid & 63, wid = tid >> 6;
  const int base = tid * 80;
  int s = 0;
  if (tid < 250) {
#pragma unroll
    for (int i = 0; i < 80; i += 4) {
      int4 c = *(const int4*)&counts[base + i];
      s += c.x + c.y + c.z + c.w;
    }
  }
  int x = s;
#pragma unroll
  for (int off = 1; off < 64; off <<= 1) {
    int t = __shfl_up(x, off, 64);
    if (lane >= off) x += t;
  }
  if (lane == 63) wsum2[wid] = x;
  __syncthreads();
  int wbase = 0;
  for (int wI = 0; wI < wid; ++wI) wbase += wsum2[wI];
  int run = wbase + x - s;
  if (tid < 250) {
#pragma unroll
    for (int i = 0; i < 80; i += 4) {
      int4 c = *(const int4*)&counts[base + i];
      int4 o;
      o.x = run;
      o.y = run + c.x;
      o.z = o.y + c.y;
      o.w = o.z + c.z;
      *(int4*)&offsets[base + i] = o;
      *(int4*)&counts[base + i] = o;       // counts becomes fill cursor
      run = o.w + c.w;
    }
  }
  if (tid == 0) {
    int tot = 0;
#pragma unroll
    for (int wI = 0; wI < 4; ++wI) tot += wsum2[wI];
    offsets[M_NODES] = tot;
  }
}

// ---------------- 3. CSR fill ----------------
__global__ __launch_bounds__(256) void fill_k(const int* __restrict__ src,
                                              const int* __restrict__ dst,
                                              int* __restrict__ cursor,
                                              int* __restrict__ esrc) {
  int e = blockIdx.x * 256 + threadIdx.x;
  if (e < N_EDGES_C) {
    int p = atomicAdd(&cursor[dst[e]], 1);
    esrc[p] = src[e];
  }
}

// ---------------- 4. aggregate: XCD-pinned panels, 8-wide idx broadcast -----
// Body x REPS (idempotent rewrite of aggb).
__global__ __launch_bounds__(256) void aggregate_k(const __bf16* __restrict__ hb,
                                                   const int* __restrict__ offs,
                                                   const int* __restrict__ esrc,
                                                   __bf16* __restrict__ aggb) {
  const int panel = blockIdx.x & 7;           // -> XCD id (round-robin dispatch)
  const int nb = blockIdx.x >> 3;             // 0..624
  const int wv = threadIdx.x >> 6;
  const int lane = threadIdx.x & 63;
  const int slot = lane >> 3;                 // 0..7: node sub-index within wave
  const int cg = lane & 7;                    // 0..7: column group (8 cols)
  const int node = nb * 32 + wv * 8 + slot;   // 625*32 = 20000 exactly

  const int beg = offs[node], end = offs[node + 1];
  const size_t pbase = (size_t)panel * 64 + cg * 8;

  for (int rep = 0; rep < REPS; ++rep) {
    float a[8] = {};
    int j = beg;
    while (j + 8 <= end) {
      const int idx = esrc[j + cg];           // 8 consecutive indices per group
      int sid[8];
#pragma unroll
      for (int g = 0; g < 8; ++g) sid[g] = __shfl(idx, (lane & 56) + g, 64);
      bf16x8 v[8];
#pragma unroll
      for (int g = 0; g < 8; ++g)
        v[g] = *(const bf16x8*)&hb[(size_t)sid[g] * DIM + pbase];
#pragma unroll
      for (int g = 0; g < 8; ++g)
#pragma unroll
        for (int q = 0; q < 8; ++q) a[q] += (float)v[g][q];
      j += 8;
    }
    for (; j < end; ++j) {
      const int s0 = esrc[j];
      bf16x8 v0 = *(const bf16x8*)&hb[(size_t)s0 * DIM + pbase];
#pragma unroll
      for (int q = 0; q < 8; ++q) a[q] += (float)v0[q];
    }
    bf16x8 o;
#pragma unroll
    for (int q = 0; q < 8; ++q) o[q] = (__bf16)a[q];
    *(bf16x8*)&aggb[(size_t)node * DIM + pbase] = o;
  }
}

// ---------------- 5. GEMM v3 (R9): body x REPS (idempotent d_out writes) ----
__global__ __launch_bounds__(256, 2) void gemm_k(const __bf16* __restrict__ A,
                                                 const __bf16* __restrict__ B,
                                                 const float* __restrict__ bias,
                                                 const float* __restrict__ norm,
                                                 float* __restrict__ C) {
  __shared__ __bf16 As[2][128 * 64];
  __shared__ __bf16 Bs[2][128 * 64];
  const int tid = threadIdx.x;
  const int lane = tid & 63;
  const int wv = tid >> 6;          // 4 waves
  const int wr = wv >> 1, wc = wv & 1;
  const int m0 = blockIdx.x * 128;
  const int n0 = blockIdx.y * 128;

  const int srow = tid >> 3;          // 0..31: row within 32-row strip
  const int scol = (tid & 7) * 8;     // 0..56: k element offset

  auto stage = [&](int buf, int kt) {
    const int kb = kt * 64 + scol;
#pragma unroll
    for (int jj = 0; jj < 4; ++jj) {
      const int lrow = jj * 32 + srow;
      int arow = m0 + lrow;
      arow = arow < M_NODES ? arow : (M_NODES - 1);     // clamp tail rows
      async16(&As[buf][lrow * 64 + scol], A + (size_t)arow * DIM + kb);
      const int brow = n0 + lrow;                       // N=512 always in range
      async16(&Bs[buf][lrow * 64 + scol], B + (size_t)brow * DIM + kb);
    }
  };

  for (int rep = 0; rep < REPS; ++rep) {
    f32x4 acc[4][4] = {};
    stage(0, 0);
    __syncthreads();

    int cur = 0;
    for (int kt = 0; kt < DIM / 64; ++kt) {
      if (kt + 1 < DIM / 64) stage(cur ^ 1, kt + 1);   // prefetch next K-tile
#pragma unroll
      for (int kk = 0; kk < 64; kk += 32) {
        bf16x8 af[4], bfr[4];
#pragma unroll
        for (int m = 0; m < 4; ++m)
          af[m] = *(const bf16x8*)&As[cur][(wr * 64 + m * 16 + (lane & 15)) * 64 + kk + (lane >> 4) * 8];
#pragma unroll
        for (int n = 0; n < 4; ++n)
          bfr[n] = *(const bf16x8*)&Bs[cur][(wc * 64 + n * 16 + (lane & 15)) * 64 + kk + (lane >> 4) * 8];
#pragma unroll
        for (int m = 0; m < 4; ++m)
#pragma unroll
          for (int n = 0; n < 4; ++n)
            acc[m][n] = __builtin_amdgcn_mfma_f32_16x16x32_bf16(af[m], bfr[n], acc[m][n], 0, 0, 0);
      }
      __syncthreads();   // drains vmcnt (next buf staged) + lgkm (cur reads done)
      cur ^= 1;
    }

    // epilogue
#pragma unroll
    for (int m = 0; m < 4; ++m) {
      const int rbase = m0 + wr * 64 + m * 16 + (lane >> 4) * 4;
#pragma unroll
      for (int r = 0; r < 4; ++r) {
        const int row = rbase + r;
        if (row < M_NODES) {
          const float nv = norm[row];
#pragma unroll
          for (int n = 0; n < 4; ++n) {
            const int col = n0 + wc * 64 + n * 16 + (lane & 15);
            float v = acc[m][n][r] * nv + bias[col];
            C[(size_t)row * DIM + col] = v > 0.f ? v : 0.f;
          }
        }
      }
    }
    __syncthreads();   // all reads of As/Bs done before next rep restages
  }
}

// ---------------- workspace layout ----------------
#define HB_OFF   0UL                     // 20,480,000 B  bf16 h*norm
#define AGG_OFF  20480000UL              // 20,480,000 B  bf16 aggregate
#define WT_OFF   40960000UL              //    524,288 B  bf16 W^T
#define CNT_OFF  41484288UL              //     80,000 B  counts -> cursor (16B aligned)
#define OFS_OFF  41564288UL              //     80,256 B  offsets[20001]
#define ESRC_OFF 41644544UL              //  1,280,000 B  CSR src indices
#define WS_NEEDED 42924544UL

extern "C" void kernel_launch(void* const* d_in, const int* in_sizes, int n_in,
                              void* d_out, int out_size, void* d_ws, size_t ws_size,
                              hipStream_t stream) {
  const float* h    = (const float*)d_in[0];
  const float* w    = (const float*)d_in[1];
  const float* bias = (const float*)d_in[2];
  const float* norm = (const float*)d_in[3];
  const int*   src  = (const int*)d_in[4];
  const int*   dst  = (const int*)d_in[5];
  float* out = (float*)d_out;

  if (ws_size < WS_NEEDED) return;  // clean failure signal instead of OOB

  char* ws = (char*)d_ws;
  __bf16* hb      = (__bf16*)(ws + HB_OFF);
  __bf16* aggb    = (__bf16*)(ws + AGG_OFF);
  __bf16* wT      = (__bf16*)(ws + WT_OFF);
  int*    counts  = (int*)(ws + CNT_OFF);
  int*    offsets = (int*)(ws + OFS_OFF);
  int*    esrc    = (int*)(ws + ESRC_OFF);

  zero_k<<<20, 256, 0, stream>>>((int4*)counts);
  pre_k<<<2048, 256, 0, stream>>>(h, w, norm, dst, hb, wT, counts);
  scan_k<<<1, 256, 0, stream>>>(counts, offsets);
  fill_k<<<1250, 256, 0, stream>>>(src, dst, counts, esrc);
  aggregate_k<<<5000, 256, 0, stream>>>(hb, offsets, esrc, aggb);
  gemm_k<<<dim3(157, 4), 256, 0, stream>>>(aggb, wT, bias, norm, out);
}

// Round 11
// 119.728 us; speedup vs baseline: 2.1818x; 2.1818x over previous
//
#include <hip/hip_runtime.h>

#define M_NODES 20000
#define N_EDGES_C 320000
#define DIM 512

typedef __attribute__((ext_vector_type(4))) float f32x4;
typedef __attribute__((ext_vector_type(4))) __bf16 bf16x4;
typedef __attribute__((ext_vector_type(8))) __bf16 bf16x8;

// ---------------- async global->LDS (16B per lane) ----------------
__device__ __forceinline__ void async16(__bf16* lds, const __bf16* g) {
  __builtin_amdgcn_global_load_lds(
      (const __attribute__((address_space(1))) void*)g,
      (__attribute__((address_space(3))) void*)lds, 16, 0, 0);
}

// ---------------- 0. zero counts ----------------
__global__ __launch_bounds__(256) void zero_k(int4* __restrict__ counts4) {
  const int i = blockIdx.x * 256 + threadIdx.x;
  if (i < M_NODES / 4) counts4[i] = int4{0, 0, 0, 0};
}

// ---------------- 1. fused pre-pass: convert + W-transpose + degree count ----
__global__ __launch_bounds__(256) void pre_k(const float* __restrict__ h,
                                             const float* __restrict__ w,
                                             const float* __restrict__ norm,
                                             const int* __restrict__ dst,
                                             __bf16* __restrict__ hb,
                                             __bf16* __restrict__ wT,
                                             int* __restrict__ counts) {
  const int bid = blockIdx.x;
  const int tid = threadIdx.x;
  const int gtid = bid * 256 + tid;
  const int gsz = gridDim.x * 256;

  // convert: hb = bf16(norm[row] * h), grid-stride over 2.56M float4 groups
  for (int i = gtid; i < M_NODES * DIM / 4; i += gsz) {
    const int elem = i * 4;
    const float s = norm[elem >> 9];
    f32x4 v = *(const f32x4*)&h[elem];
    bf16x4 o;
    o.x = (__bf16)(v.x * s);
    o.y = (__bf16)(v.y * s);
    o.z = (__bf16)(v.z * s);
    o.w = (__bf16)(v.w * s);
    *(bf16x4*)&hb[elem] = o;
  }

  // weight transpose: blocks 0..255 handle one 32x32 tile each
  if (bid < 256) {
    __shared__ float tile[32][33];
    const int bx = (bid & 15) * 32, by = (bid >> 4) * 32;
    const int tx = tid & 31, ty8 = tid >> 5;
#pragma unroll
    for (int st = 0; st < 4; ++st) {
      const int r = ty8 + st * 8;
      tile[r][tx] = w[(by + r) * DIM + bx + tx];
    }
    __syncthreads();
#pragma unroll
    for (int st = 0; st < 4; ++st) {
      const int r = ty8 + st * 8;
      wT[(bx + r) * DIM + by + tx] = (__bf16)tile[tx][r];
    }
  }

  // degree count
  for (int e = gtid; e < N_EDGES_C; e += gsz) atomicAdd(&counts[dst[e]], 1);
}

// ---------------- 2. scan: 1 block, 250 threads x 80 elements ----------------
__global__ __launch_bounds__(256) void scan_k(int* __restrict__ counts,
                                              int* __restrict__ offsets) {
  __shared__ int wsum2[4];
  const int tid = threadIdx.x;
  const int lane = tid & 63, wid = tid >> 6;
  const int base = tid * 80;
  int s = 0;
  if (tid < 250) {
#pragma unroll
    for (int i = 0; i < 80; i += 4) {
      int4 c = *(const int4*)&counts[base + i];
      s += c.x + c.y + c.z + c.w;
    }
  }
  int x = s;
#pragma unroll
  for (int off = 1; off < 64; off <<= 1) {
    int t = __shfl_up(x, off, 64);
    if (lane >= off) x += t;
  }
  if (lane == 63) wsum2[wid] = x;
  __syncthreads();
  int wbase = 0;
  for (int wI = 0; wI < wid; ++wI) wbase += wsum2[wI];
  int run = wbase + x - s;
  if (tid < 250) {
#pragma unroll
    for (int i = 0; i < 80; i += 4) {
      int4 c = *(const int4*)&counts[base + i];
      int4 o;
      o.x = run;
      o.y = run + c.x;
      o.z = o.y + c.y;
      o.w = o.z + c.z;
      *(int4*)&offsets[base + i] = o;
      *(int4*)&counts[base + i] = o;       // counts becomes fill cursor
      run = o.w + c.w;
    }
  }
  if (tid == 0) {
    int tot = 0;
#pragma unroll
    for (int wI = 0; wI < 4; ++wI) tot += wsum2[wI];
    offsets[M_NODES] = tot;
  }
}

// ---------------- 3. CSR fill ----------------
__global__ __launch_bounds__(256) void fill_k(const int* __restrict__ src,
                                              const int* __restrict__ dst,
                                              int* __restrict__ cursor,
                                              int* __restrict__ esrc) {
  int e = blockIdx.x * 256 + threadIdx.x;
  if (e < N_EDGES_C) {
    int p = atomicAdd(&cursor[dst[e]], 1);
    esrc[p] = src[e];
  }
}

// ---------------- 4. aggregate: XCD-pinned panels, 8-wide idx broadcast -----
// UNCHANGED (single-change discipline: only gemm edited this round).
__global__ __launch_bounds__(256) void aggregate_k(const __bf16* __restrict__ hb,
                                                   const int* __restrict__ offs,
                                                   const int* __restrict__ esrc,
                                                   __bf16* __restrict__ aggb) {
  const int panel = blockIdx.x & 7;           // -> XCD id (round-robin dispatch)
  const int nb = blockIdx.x >> 3;             // 0..624
  const int wv = threadIdx.x >> 6;
  const int lane = threadIdx.x & 63;
  const int slot = lane >> 3;                 // 0..7: node sub-index within wave
  const int cg = lane & 7;                    // 0..7: column group (8 cols)
  const int node = nb * 32 + wv * 8 + slot;   // 625*32 = 20000 exactly

  const int beg = offs[node], end = offs[node + 1];
  const size_t pbase = (size_t)panel * 64 + cg * 8;

  float a[8] = {};
  int j = beg;
  while (j + 8 <= end) {
    const int idx = esrc[j + cg];             // 8 consecutive indices per group
    int sid[8];
#pragma unroll
    for (int g = 0; g < 8; ++g) sid[g] = __shfl(idx, (lane & 56) + g, 64);
    bf16x8 v[8];
#pragma unroll
    for (int g = 0; g < 8; ++g)
      v[g] = *(const bf16x8*)&hb[(size_t)sid[g] * DIM + pbase];
#pragma unroll
    for (int g = 0; g < 8; ++g)
#pragma unroll
      for (int q = 0; q < 8; ++q) a[q] += (float)v[g][q];
    j += 8;
  }
  for (; j < end; ++j) {
    const int s0 = esrc[j];
    bf16x8 v0 = *(const bf16x8*)&hb[(size_t)s0 * DIM + pbase];
#pragma unroll
    for (int q = 0; q < 8; ++q) a[q] += (float)v0[q];
  }
  bf16x8 o;
#pragma unroll
  for (int q = 0; q < 8; ++q) o[q] = (__bf16)a[q];
  *(bf16x8*)&aggb[(size_t)node * DIM + pbase] = o;
}

// ---------------- 5. GEMM v4: out = relu(norm * (aggb @ W) + bias) ----------
// R10 measured (v3, x3): 37.8us/rep, MfmaUtil 10.8%, Occ 14%, 3.9M bank-
// conflict cyc/rep, BW 2.38 TB/s -> parallelism-starved + 16-way LDS read
// conflict (row stride 128B, G4 case). v4:
//  - BM=64, BN=128, BK=64, dbuf LDS = 48 KB -> 3 blocks/CU resident
//    (12 waves/CU) for inter-block overlap of barrier drains; grid 313x4.
//  - XOR swizzle (rule #21, both sides): stage reads global chunk
//    (tid&7)^(srow&7) into LINEAR LDS; ds_read uses chunk c^(row&7).
//    Rows spread over 8 16B slots -> 2-way (free) instead of 16-way.
__global__ __launch_bounds__(256, 2) void gemm_k(const __bf16* __restrict__ A,
                                                 const __bf16* __restrict__ B,
                                                 const float* __restrict__ bias,
                                                 const float* __restrict__ norm,
                                                 float* __restrict__ C) {
  __shared__ __bf16 As[2][64 * 64];
  __shared__ __bf16 Bs[2][128 * 64];
  const int tid = threadIdx.x;
  const int lane = tid & 63;
  const int wv = tid >> 6;          // 4 waves: wr in {0,1} x wc in {0,1}
  const int wr = wv >> 1, wc = wv & 1;
  const int m0 = blockIdx.x * 64;
  const int n0 = blockIdx.y * 128;

  f32x4 acc[2][4] = {};

  const int srow = tid >> 3;                    // 0..31: row within 32-row strip
  const int scol = ((tid & 7) ^ (srow & 7)) * 8;  // pre-swizzled source chunk

  auto stage = [&](int buf, int kt) {
    const int kb = kt * 64 + scol;
#pragma unroll
    for (int jj = 0; jj < 2; ++jj) {            // A: 64 rows
      const int lrow = jj * 32 + srow;
      int arow = m0 + lrow;
      arow = arow < M_NODES ? arow : (M_NODES - 1);   // clamp tail rows
      async16(&As[buf][lrow * 64 + (tid & 7) * 8], A + (size_t)arow * DIM + kb);
    }
#pragma unroll
    for (int jj = 0; jj < 4; ++jj) {            // B: 128 rows (always in range)
      const int lrow = jj * 32 + srow;
      async16(&Bs[buf][lrow * 64 + (tid & 7) * 8], B + (size_t)(n0 + lrow) * DIM + kb);
    }
  };

  stage(0, 0);
  __syncthreads();

  int cur = 0;
  for (int kt = 0; kt < DIM / 64; ++kt) {
    if (kt + 1 < DIM / 64) stage(cur ^ 1, kt + 1);   // prefetch next K-tile
#pragma unroll
    for (int kk = 0; kk < 64; kk += 32) {
      const int c = (kk >> 3) + (lane >> 4);         // 16B chunk index 0..7
      bf16x8 af[2], bfr[4];
#pragma unroll
      for (int m = 0; m < 2; ++m) {
        const int r = wr * 32 + m * 16 + (lane & 15);
        af[m] = *(const bf16x8*)&As[cur][r * 64 + ((c ^ (r & 7)) * 8)];
      }
#pragma unroll
      for (int n = 0; n < 4; ++n) {
        const int r = wc * 64 + n * 16 + (lane & 15);
        bfr[n] = *(const bf16x8*)&Bs[cur][r * 64 + ((c ^ (r & 7)) * 8)];
      }
#pragma unroll
      for (int m = 0; m < 2; ++m)
#pragma unroll
        for (int n = 0; n < 4; ++n)
          acc[m][n] = __builtin_amdgcn_mfma_f32_16x16x32_bf16(af[m], bfr[n], acc[m][n], 0, 0, 0);
    }
    __syncthreads();   // drains vmcnt (next buf staged) + lgkm (cur reads done)
    cur ^= 1;
  }

  // epilogue: C row = (lane>>4)*4 + reg, col = lane&15 within each 16x16 frag
#pragma unroll
  for (int m = 0; m < 2; ++m) {
    const int rbase = m0 + wr * 32 + m * 16 + (lane >> 4) * 4;
#pragma unroll
    for (int r = 0; r < 4; ++r) {
      const int row = rbase + r;
      if (row < M_NODES) {
        const float nv = norm[row];
#pragma unroll
        for (int n = 0; n < 4; ++n) {
          const int col = n0 + wc * 64 + n * 16 + (lane & 15);
          float v = acc[m][n][r] * nv + bias[col];
          C[(size_t)row * DIM + col] = v > 0.f ? v : 0.f;
        }
      }
    }
  }
}

// ---------------- workspace layout ----------------
#define HB_OFF   0UL                     // 20,480,000 B  bf16 h*norm
#define AGG_OFF  20480000UL              // 20,480,000 B  bf16 aggregate
#define WT_OFF   40960000UL              //    524,288 B  bf16 W^T
#define CNT_OFF  41484288UL              //     80,000 B  counts -> cursor (16B aligned)
#define OFS_OFF  41564288UL              //     80,256 B  offsets[20001]
#define ESRC_OFF 41644544UL              //  1,280,000 B  CSR src indices
#define WS_NEEDED 42924544UL

extern "C" void kernel_launch(void* const* d_in, const int* in_sizes, int n_in,
                              void* d_out, int out_size, void* d_ws, size_t ws_size,
                              hipStream_t stream) {
  const float* h    = (const float*)d_in[0];
  const float* w    = (const float*)d_in[1];
  const float* bias = (const float*)d_in[2];
  const float* norm = (const float*)d_in[3];
  const int*   src  = (const int*)d_in[4];
  const int*   dst  = (const int*)d_in[5];
  float* out = (float*)d_out;

  if (ws_size < WS_NEEDED) return;  // clean failure signal instead of OOB

  char* ws = (char*)d_ws;
  __bf16* hb      = (__bf16*)(ws + HB_OFF);
  __bf16* aggb    = (__bf16*)(ws + AGG_OFF);
  __bf16* wT      = (__bf16*)(ws + WT_OFF);
  int*    counts  = (int*)(ws + CNT_OFF);
  int*    offsets = (int*)(ws + OFS_OFF);
  int*    esrc    = (int*)(ws + ESRC_OFF);

  zero_k<<<20, 256, 0, stream>>>((int4*)counts);
  pre_k<<<2048, 256, 0, stream>>>(h, w, norm, dst, hb, wT, counts);
  scan_k<<<1, 256, 0, stream>>>(counts, offsets);
  fill_k<<<1250, 256, 0, stream>>>(src, dst, counts, esrc);
  aggregate_k<<<5000, 256, 0, stream>>>(hb, offsets, esrc, aggb);
  gemm_k<<<dim3(313, 4), 256, 0, stream>>>(aggb, wT, bias, norm, out);
}